// Round 7
// baseline (133.105 us; speedup 1.0000x reference)
//
#include <hip/hip_runtime.h>
#include <hip/hip_bf16.h>

#define HH 256
#define WW 256
#define CC 128
#define NN 4
#define NSS 5
#define LN2F 0.6931471805599453f
#define FSCALE 3.79828245f      // sqrt(10*log2(e)); dot scales by 14.4269504089
#define EPSI 1e-6f
#define ROWB (WW * CC * 2)      // 65536 B per image row (256 px * 256 B)

typedef __attribute__((ext_vector_type(4))) float f32x4;
typedef __attribute__((ext_vector_type(8))) short short8v;

// ---------------- Kernel A: L2-normalize over C (x FSCALE), NCHW(f32) -> NHWC(bf16) -------
__global__ __launch_bounds__(256) void norm_pack(const float* __restrict__ feat,
                                                 __hip_bfloat16* __restrict__ out) {
    __shared__ float lds[64][CC + 2];
    __shared__ float psum[4][64];
    __shared__ float inv[64];
    int bid = blockIdx.x;            // n*1024 + h*4 + wq
    int wq = bid & 3;
    int h = (bid >> 2) & 255;
    int n = bid >> 10;
    int tid = threadIdx.x;
    int p = tid & 63;
    int cg = tid >> 6;
    size_t base = ((size_t)(n * CC) * HH + h) * WW + wq * 64 + p;
    float ss = 0.f;
    #pragma unroll
    for (int i = 0; i < 32; ++i) {
        int c = cg * 32 + i;
        float v = feat[base + (size_t)c * (HH * WW)];
        lds[p][c] = v;
        ss += v * v;
    }
    psum[cg][p] = ss;
    __syncthreads();
    if (tid < 64) {
        float s = psum[0][tid] + psum[1][tid] + psum[2][tid] + psum[3][tid];
        inv[tid] = FSCALE / fmaxf(sqrtf(s), 1e-12f);
    }
    __syncthreads();
    __hip_bfloat16* dst = out + (((size_t)n * HH + h) * WW + wq * 64) * CC;
    #pragma unroll
    for (int k = 0; k < 4; ++k) {
        int j = (k * 256 + tid) * 8;
        int pp = j >> 7;
        int c0 = j & 127;
        float iv = inv[pp];
        __hip_bfloat16 tmp[8];
        #pragma unroll
        for (int i = 0; i < 8; ++i)
            tmp[i] = __float2bfloat16(lds[pp][c0 + i] * iv);
        *(uint4*)(dst + j) = *(uint4*)tmp;
    }
}

// ---------------- Kernel B: barrier-free banded-Gram MFMA loss ----------------
// 2048 blocks x 4 waves; each wave INDEPENDENT: owns 2 rows x 16 cols.
// B-tiles (-8,+8) loaded straight to VGPRs (L2/L3-hot), 2-deep reg double-buffer:
// loads for row r+1 issue before compute of row r. No LDS staging, no barriers.
// Select-before-exp: per (nloc,rr) at most one of the two tiles' cells is
// band-valid (dx differs by 16) -> one exp2 per rr. Mask applied in epilogue.
// Features pre-scaled by FSCALE => MFMA output d = logit*log2(e)*10 directly.
// C layout (m89): col=lane&15 (neighbor), row=(lane>>4)*4+reg (own).
__global__ __launch_bounds__(256, 3) void loss_mfma(const char* __restrict__ fn,
                                                    float* __restrict__ out) {
    int bid = blockIdx.x;
    int swz = (bid & 7) * 256 + (bid >> 3);   // 2048 blocks, bijective XCD swizzle
    int n  = swz >> 9;
    int hp = (swz >> 2) & 127;
    int q  = swz & 3;
    int row0 = hp * 2;
    int tid = threadIdx.x;
    int wave = tid >> 6, lane = tid & 63;
    int nloc = lane & 15, kq = lane >> 4;
    int wbase = q * 64 + wave * 16;

    const char* img = fn + (size_t)n * ((size_t)HH * ROWB);

    // A fragments: own rows row0,row0+1 at col wbase+nloc
    short8v a0[4], a1[4];
    {
        const char* pb0 = img + (size_t)row0 * ROWB + (wbase + nloc) * 256;
        #pragma unroll
        for (int kb = 0; kb < 4; ++kb) a0[kb] = *(const short8v*)(pb0 + ((kb * 4 + kq) << 4));
        const char* pb1 = pb0 + ROWB;
        #pragma unroll
        for (int kb = 0; kb < 4; ++kb) a1[kb] = *(const short8v*)(pb1 + ((kb * 4 + kq) << 4));
    }

    // B global byte-offsets within a row (2 tiles at wbase-8, wbase+8), col-clamped
    int bo[2][4];
    #pragma unroll
    for (int j = 0; j < 2; ++j) {
        int colr = wbase - 8 + 16 * j + nloc;
        int cc = min(max(colr, 0), WW - 1);
        #pragma unroll
        for (int kb = 0; kb < 4; ++kb)
            bo[j][kb] = cc * 256 + ((kb * 4 + kq) << 4);
    }

    // selection (use tile1?) + validity per rr; dy-invariant, mask applied at end
    unsigned msel = 0, mb = 0;
    #pragma unroll
    for (int rr = 0; rr < 4; ++rr) {
        int rm = kq * 4 + rr;
        int dx0 = -8 + nloc - rm, dx1 = 8 + nloc - rm;
        int nc0 = wbase - 8 + nloc, nc1 = wbase + 8 + nloc;
        bool v0 = dx0 >= -NSS && dx0 <= NSS && nc0 >= 0 && nc0 < WW;
        bool v1 = dx1 >= -NSS && dx1 <= NSS && nc1 >= 0 && nc1 < WW;
        if (v1) msel |= 1u << rr;
        if (v0 || v1) mb |= 1u << rr;
    }

    float ea0[4], ea1[4], ds0[4], ds1[4];
    #pragma unroll
    for (int rr = 0; rr < 4; ++rr) {
        ea0[rr] = EPSI; ea1[rr] = EPSI; ds0[rr] = 0.f; ds1[rr] = 0.f;
    }

#define LOADB(B0_, B1_, rowp_) { \
    _Pragma("unroll") for (int kb = 0; kb < 4; ++kb) (B0_)[kb] = *(const short8v*)((rowp_) + bo[0][kb]); \
    _Pragma("unroll") for (int kb = 0; kb < 4; ++kb) (B1_)[kb] = *(const short8v*)((rowp_) + bo[1][kb]); \
}

#define COMPUTE(B0_, B1_, r_) { \
    if ((r_) <= row0 + NSS) { \
        f32x4 c0 = {0.f, 0.f, 0.f, 0.f}, c1 = {0.f, 0.f, 0.f, 0.f}; \
        __builtin_amdgcn_s_setprio(1); \
        _Pragma("unroll") for (int kb = 0; kb < 4; ++kb) \
            c0 = __builtin_amdgcn_mfma_f32_16x16x32_bf16(a0[kb], (B0_)[kb], c0, 0, 0, 0); \
        _Pragma("unroll") for (int kb = 0; kb < 4; ++kb) \
            c1 = __builtin_amdgcn_mfma_f32_16x16x32_bf16(a0[kb], (B1_)[kb], c1, 0, 0, 0); \
        __builtin_amdgcn_s_setprio(0); \
        _Pragma("unroll") for (int rr = 0; rr < 4; ++rr) { \
            float d_ = ((msel >> rr) & 1) ? c1[rr] : c0[rr]; \
            ea0[rr] += exp2f(d_); ds0[rr] += d_; \
        } \
    } \
    if ((r_) >= row0 + 1 - NSS) { \
        f32x4 c0 = {0.f, 0.f, 0.f, 0.f}, c1 = {0.f, 0.f, 0.f, 0.f}; \
        __builtin_amdgcn_s_setprio(1); \
        _Pragma("unroll") for (int kb = 0; kb < 4; ++kb) \
            c0 = __builtin_amdgcn_mfma_f32_16x16x32_bf16(a1[kb], (B0_)[kb], c0, 0, 0, 0); \
        _Pragma("unroll") for (int kb = 0; kb < 4; ++kb) \
            c1 = __builtin_amdgcn_mfma_f32_16x16x32_bf16(a1[kb], (B1_)[kb], c1, 0, 0, 0); \
        __builtin_amdgcn_s_setprio(0); \
        _Pragma("unroll") for (int rr = 0; rr < 4; ++rr) { \
            float d_ = ((msel >> rr) & 1) ? c1[rr] : c0[rr]; \
            ea1[rr] += exp2f(d_); ds1[rr] += d_; \
        } \
    } \
}

    int rs = max(row0 - NSS, 0);
    int re = min(row0 + 1 + NSS, HH - 1);

    short8v p0[4], p1[4], q0[4], q1[4];
    LOADB(p0, p1, img + (size_t)rs * ROWB);
    int r = rs;
    for (;;) {
        if (r < re) LOADB(q0, q1, img + (size_t)(r + 1) * ROWB);
        COMPUTE(p0, p1, r);
        if (++r > re) break;
        if (r < re) LOADB(p0, p1, img + (size_t)(r + 1) * ROWB);
        COMPUTE(q0, q1, r);
        if (++r > re) break;
    }

    // Epilogue: deferred masks, weights, reduce
    float acc = 0.f;
    #pragma unroll
    for (int t = 0; t < 2; ++t) {
        int row = row0 + t;
        float nvd = (float)(min(NSS, row) + min(NSS, HH - 1 - row) + 1);
        #pragma unroll
        for (int rr = 0; rr < 4; ++rr) {
            int wm = wbase + kq * 4 + rr;
            int nwd = min(NSS, wm) + min(NSS, WW - 1 - wm) + 1;
            float iw = 1.0f / (nvd * (float)nwd);
            float m_ = (mb & (1u << rr)) ? 1.0f : 0.0f;
            float ea = t ? ea1[rr] : ea0[rr];
            float ds = t ? ds1[rr] : ds0[rr];
            acc += m_ * iw * (nvd * __logf(ea) - LN2F * ds);
        }
    }
    float tot = acc * (1.0f / (4.0f * 65536.0f));
    #pragma unroll
    for (int off = 32; off >= 1; off >>= 1)
        tot += __shfl_down(tot, off);
    __shared__ float wsum[4];
    if (lane == 0) wsum[wave] = tot;
    __syncthreads();
    if (tid == 0) atomicAdd(out, wsum[0] + wsum[1] + wsum[2] + wsum[3]);
}

extern "C" void kernel_launch(void* const* d_in, const int* in_sizes, int n_in,
                              void* d_out, int out_size, void* d_ws, size_t ws_size,
                              hipStream_t stream) {
    const float* feat = (const float*)d_in[0];
    float* out = (float*)d_out;
    __hip_bfloat16* fnorm = (__hip_bfloat16*)d_ws;  // 64MB

    hipMemsetAsync(d_out, 0, sizeof(float), stream);
    norm_pack<<<NN * HH * (WW / 64), 256, 0, stream>>>(feat, fnorm);
    loss_mfma<<<NN * HH * 2, 256, 0, stream>>>((const char*)fnorm, out);
}

// Round 8
// 81.369 us; speedup vs baseline: 1.6358x; 1.6358x over previous
//
#include <hip/hip_runtime.h>
#include <hip/hip_bf16.h>

#define HH 256
#define WW 256
#define CC 128
#define NN 4
#define NSS 5
#define LN2F 0.6931471805599453f
#define FSCALE 3.79828245f      // sqrt(10*log2(e)); dot scales by 14.4269504089
#define EPSI 1e-6f
#define ROWB (WW * CC * 2)      // 65536 B per image row (256 px * 256 B)
#define SC 80                   // staged cols per row window (c0-8 .. c0+71)
#define SBYTES (SC * 256)       // 20480 B per staged row

typedef __attribute__((ext_vector_type(4))) float f32x4;
typedef __attribute__((ext_vector_type(8))) short short8v;

__device__ __forceinline__ void gload_lds16(const void* g, void* l) {
    __builtin_amdgcn_global_load_lds(
        (const __attribute__((address_space(1))) unsigned int*)g,
        (__attribute__((address_space(3))) unsigned int*)l, 16, 0, 0);
}

// ---------------- Kernel A: L2-normalize over C (x FSCALE), NCHW(f32) -> NHWC(bf16) -------
// granule-swizzled: 16B granule g of pixel w stored at slot g^(w&7)
__global__ __launch_bounds__(256) void norm_pack(const float* __restrict__ feat,
                                                 __hip_bfloat16* __restrict__ out) {
    __shared__ float lds[64][CC + 2];
    __shared__ float psum[4][64];
    __shared__ float inv[64];
    int bid = blockIdx.x;            // n*1024 + h*4 + wq
    int wq = bid & 3;
    int h = (bid >> 2) & 255;
    int n = bid >> 10;
    int tid = threadIdx.x;
    int p = tid & 63;
    int cg = tid >> 6;
    size_t base = ((size_t)(n * CC) * HH + h) * WW + wq * 64 + p;
    float ss = 0.f;
    #pragma unroll
    for (int i = 0; i < 32; ++i) {
        int c = cg * 32 + i;
        float v = feat[base + (size_t)c * (HH * WW)];
        lds[p][c] = v;
        ss += v * v;
    }
    psum[cg][p] = ss;
    __syncthreads();
    if (tid < 64) {
        float s = psum[0][tid] + psum[1][tid] + psum[2][tid] + psum[3][tid];
        inv[tid] = FSCALE / fmaxf(sqrtf(s), 1e-12f);
    }
    __syncthreads();
    __hip_bfloat16* dst = out + (((size_t)n * HH + h) * WW + wq * 64) * CC;
    #pragma unroll
    for (int k = 0; k < 4; ++k) {
        int j = (k * 256 + tid) * 8;
        int pp = j >> 7;
        int c0 = j & 127;
        int g = c0 >> 3;
        int gs = g ^ (pp & 7);           // (wq*64+pp)&7 == pp&7
        float iv = inv[pp];
        __hip_bfloat16 tmp[8];
        #pragma unroll
        for (int i = 0; i < 8; ++i)
            tmp[i] = __float2bfloat16(lds[pp][c0 + i] * iv);
        *(uint4*)(dst + pp * 128 + gs * 8) = *(uint4*)tmp;
    }
}

// ---------------- Kernel B: LDS-staged banded-Gram MFMA loss, 4 rows/wave ----------------
// Block = 4 waves (256 thr), owns 4 rows x 64 cols; wave = 4 own rows x 16 cols.
// Two B-tiles (-8,+8) per staged row shared by ALL 4 A-row fragments:
// LDS-read bytes/own-px = 14 rows x 8KB / 64 px = 1.75KB (was 3KB in R6).
// 2x20KB double-buffer, 5 gload_lds/thread/row, counted vmcnt(5).
// Select-before-exp (msel): per (lane,rr) at most one of the two tiles is in-band.
// Masks/weights deferred to epilogue. Features pre-scaled so exp(logit)=2^d.
// C layout (m89): col=lane&15 (neighbor), row=(lane>>4)*4+reg (own).
__global__ __launch_bounds__(256, 2) void loss_mfma(const char* __restrict__ fn,
                                                    float* __restrict__ out) {
    extern __shared__ char smem[];
    __shared__ float wsum[4];
    int bid = blockIdx.x;
    int swz = (bid & 7) * 128 + (bid >> 3);   // 1024 blocks, bijective XCD swizzle
    int n  = swz >> 8;
    int rg = (swz >> 2) & 63;
    int q  = swz & 3;
    int row0 = rg * 4;
    int c0 = q * 64;
    int tid = threadIdx.x;
    int wave = tid >> 6, lane = tid & 63;
    int nloc = lane & 15, kq = lane >> 4;
    int wbase = c0 + wave * 16;
    int sc0 = c0 - 8;

    const char* img = fn + (size_t)n * ((size_t)HH * ROWB);

    // A fragments: own rows row0..row0+3 at col wbase+nloc (swizzled layout)
    short8v a0[4], a1[4], a2[4], a3[4];
    {
        int px = wbase + nloc;
        const char* pb = img + (size_t)row0 * ROWB + px * 256;
        #pragma unroll
        for (int kb = 0; kb < 4; ++kb) a0[kb] = *(const short8v*)(pb + (((kb * 4 + kq) ^ (px & 7)) << 4));
        pb += ROWB;
        #pragma unroll
        for (int kb = 0; kb < 4; ++kb) a1[kb] = *(const short8v*)(pb + (((kb * 4 + kq) ^ (px & 7)) << 4));
        pb += ROWB;
        #pragma unroll
        for (int kb = 0; kb < 4; ++kb) a2[kb] = *(const short8v*)(pb + (((kb * 4 + kq) ^ (px & 7)) << 4));
        pb += ROWB;
        #pragma unroll
        for (int kb = 0; kb < 4; ++kb) a3[kb] = *(const short8v*)(pb + (((kb * 4 + kq) ^ (px & 7)) << 4));
    }

    // B-fragment LDS offsets (tiles at wbase-8, wbase+8), buffer-local, swizzle-matched
    int boff[2][4];
    #pragma unroll
    for (int j = 0; j < 2; ++j) {
        int colr = wbase - 8 + 16 * j + nloc;     // in [c0-8, c0+71]
        int lcol = colr - sc0;                    // 0..79
        int cc = min(max(colr, 0), WW - 1);
        #pragma unroll
        for (int kb = 0; kb < 4; ++kb)
            boff[j][kb] = lcol * 256 + (((kb * 4 + kq) ^ (cc & 7)) << 4);
    }

    // selection (tile1 valid?) + any-valid bits per rr; dy/row-invariant
    unsigned msel = 0, mb = 0;
    #pragma unroll
    for (int rr = 0; rr < 4; ++rr) {
        int rm = kq * 4 + rr;
        int dx0 = -8 + nloc - rm, dx1 = 8 + nloc - rm;
        int nc0 = wbase - 8 + nloc, nc1 = wbase + 8 + nloc;
        bool v0 = dx0 >= -NSS && dx0 <= NSS && nc0 >= 0 && nc0 < WW;
        bool v1 = dx1 >= -NSS && dx1 <= NSS && nc1 >= 0 && nc1 < WW;
        if (v1) msel |= 1u << rr;
        if (v0 || v1) mb |= 1u << rr;
    }

    // staging addresses: 1280 16B units, 5 per thread
    int ss0, ss1, ss2, ss3, ss4;
    {
        int c_, cc_;
        c_ = tid;          cc_ = min(max(sc0 + (c_ >> 4), 0), WW - 1); ss0 = cc_ * 256 + ((c_ & 15) << 4);
        c_ = 256 + tid;    cc_ = min(max(sc0 + (c_ >> 4), 0), WW - 1); ss1 = cc_ * 256 + ((c_ & 15) << 4);
        c_ = 512 + tid;    cc_ = min(max(sc0 + (c_ >> 4), 0), WW - 1); ss2 = cc_ * 256 + ((c_ & 15) << 4);
        c_ = 768 + tid;    cc_ = min(max(sc0 + (c_ >> 4), 0), WW - 1); ss3 = cc_ * 256 + ((c_ & 15) << 4);
        c_ = 1024 + tid;   cc_ = min(max(sc0 + (c_ >> 4), 0), WW - 1); ss4 = cc_ * 256 + ((c_ & 15) << 4);
    }
#define STAGE(rr_, buf_) { \
    const char* srow_ = img + (size_t)(rr_) * ROWB; \
    gload_lds16(srow_ + ss0, (buf_) + (tid << 4)); \
    gload_lds16(srow_ + ss1, (buf_) + ((256 + tid) << 4)); \
    gload_lds16(srow_ + ss2, (buf_) + ((512 + tid) << 4)); \
    gload_lds16(srow_ + ss3, (buf_) + ((768 + tid) << 4)); \
    gload_lds16(srow_ + ss4, (buf_) + ((1024 + tid) << 4)); \
}

    float ea0[4], ea1[4], ea2[4], ea3[4];
    float ds0[4], ds1[4], ds2[4], ds3[4];
    #pragma unroll
    for (int rr = 0; rr < 4; ++rr) {
        ea0[rr] = EPSI; ea1[rr] = EPSI; ea2[rr] = EPSI; ea3[rr] = EPSI;
        ds0[rr] = 0.f;  ds1[rr] = 0.f;  ds2[rr] = 0.f;  ds3[rr] = 0.f;
    }

#define COMPUTE_T(T_, A_, EA_, DS_) \
    if (r >= row0 + (T_) - NSS && r <= row0 + (T_) + NSS) { \
        f32x4 c0 = {0.f, 0.f, 0.f, 0.f}, c1 = {0.f, 0.f, 0.f, 0.f}; \
        __builtin_amdgcn_s_setprio(1); \
        _Pragma("unroll") for (int kb = 0; kb < 4; ++kb) \
            c0 = __builtin_amdgcn_mfma_f32_16x16x32_bf16(A_[kb], b0[kb], c0, 0, 0, 0); \
        _Pragma("unroll") for (int kb = 0; kb < 4; ++kb) \
            c1 = __builtin_amdgcn_mfma_f32_16x16x32_bf16(A_[kb], b1[kb], c1, 0, 0, 0); \
        __builtin_amdgcn_s_setprio(0); \
        _Pragma("unroll") for (int rr = 0; rr < 4; ++rr) { \
            float d_ = ((msel >> rr) & 1) ? c1[rr] : c0[rr]; \
            EA_[rr] += exp2f(d_); DS_[rr] += d_; \
        } \
    }

    int rs = max(row0 - NSS, 0);
    int re = min(row0 + 3 + NSS, HH - 1);

    STAGE(rs, smem);

    for (int r = rs; r <= re; ++r) {
        char* cbuf = smem + ((r - rs) & 1) * SBYTES;
        if (r < re) {
            char* nbuf = smem + ((((r - rs) & 1) ^ 1) * SBYTES);
            STAGE(r + 1, nbuf);
            asm volatile("s_waitcnt vmcnt(5)" ::: "memory");  // row r done; r+1 in flight
        } else {
            asm volatile("s_waitcnt vmcnt(0)" ::: "memory");
        }
        __builtin_amdgcn_s_barrier();
        asm volatile("" ::: "memory");

        short8v b0[4], b1[4];
        #pragma unroll
        for (int kb = 0; kb < 4; ++kb) b0[kb] = *(const short8v*)(cbuf + boff[0][kb]);
        #pragma unroll
        for (int kb = 0; kb < 4; ++kb) b1[kb] = *(const short8v*)(cbuf + boff[1][kb]);

        COMPUTE_T(0, a0, ea0, ds0)
        COMPUTE_T(1, a1, ea1, ds1)
        COMPUTE_T(2, a2, ea2, ds2)
        COMPUTE_T(3, a3, ea3, ds3)

        __builtin_amdgcn_s_barrier();
    }

    // Epilogue: deferred masks, weights, reduce
    float acc = 0.f;
#define EPI_T(T_, EA_, DS_) { \
    int row = row0 + (T_); \
    float nvd = (float)(min(NSS, row) + min(NSS, HH - 1 - row) + 1); \
    _Pragma("unroll") for (int rr = 0; rr < 4; ++rr) { \
        int wm = wbase + kq * 4 + rr; \
        int nwd = min(NSS, wm) + min(NSS, WW - 1 - wm) + 1; \
        float iw = 1.0f / (nvd * (float)nwd); \
        float m_ = (mb & (1u << rr)) ? 1.0f : 0.0f; \
        acc += m_ * iw * (nvd * __logf(EA_[rr]) - LN2F * DS_[rr]); \
    } \
}
    EPI_T(0, ea0, ds0)
    EPI_T(1, ea1, ds1)
    EPI_T(2, ea2, ds2)
    EPI_T(3, ea3, ds3)

    float tot = acc * (1.0f / (4.0f * 65536.0f));
    #pragma unroll
    for (int off = 32; off >= 1; off >>= 1)
        tot += __shfl_down(tot, off);
    if (lane == 0) wsum[wave] = tot;
    __syncthreads();
    if (tid == 0) atomicAdd(out, wsum[0] + wsum[1] + wsum[2] + wsum[3]);
}

extern "C" void kernel_launch(void* const* d_in, const int* in_sizes, int n_in,
                              void* d_out, int out_size, void* d_ws, size_t ws_size,
                              hipStream_t stream) {
    const float* feat = (const float*)d_in[0];
    float* out = (float*)d_out;
    __hip_bfloat16* fnorm = (__hip_bfloat16*)d_ws;  // 64MB

    hipFuncSetAttribute(reinterpret_cast<const void*>(&loss_mfma),
                        hipFuncAttributeMaxDynamicSharedMemorySize, 2 * SBYTES);

    hipMemsetAsync(d_out, 0, sizeof(float), stream);
    norm_pack<<<NN * HH * (WW / 64), 256, 0, stream>>>(feat, fnorm);
    loss_mfma<<<NN * 64 * 4, 256, 2 * SBYTES, stream>>>((const char*)fnorm, out);
}

// Round 9
// 80.214 us; speedup vs baseline: 1.6594x; 1.0144x over previous
//
#include <hip/hip_runtime.h>
#include <hip/hip_bf16.h>

#define HH 256
#define WW 256
#define CC 128
#define NN 4
#define NSS 5
#define LN2F 0.6931471805599453f
#define FSCALE 3.79828245f      // sqrt(10*log2(e)); dot scales by 14.4269504089
#define EPSI 1e-6f
#define ROWB (WW * CC * 2)      // 65536 B per image row (256 px * 256 B)
#define SC 80                   // staged cols per row window (c0-8 .. c0+71)
#define SBYTES (SC * 256)       // 20480 B per staged row

typedef __attribute__((ext_vector_type(4))) float f32x4;
typedef __attribute__((ext_vector_type(8))) short short8v;

__device__ __forceinline__ void gload_lds16(const void* g, void* l) {
    __builtin_amdgcn_global_load_lds(
        (const __attribute__((address_space(1))) unsigned int*)g,
        (__attribute__((address_space(3))) unsigned int*)l, 16, 0, 0);
}

// ---------------- Kernel A: L2-normalize over C (x FSCALE), NCHW(f32) -> NHWC(bf16) -------
// granule-swizzled: 16B granule g of pixel w stored at slot g^(w&7)
__global__ __launch_bounds__(256) void norm_pack(const float* __restrict__ feat,
                                                 __hip_bfloat16* __restrict__ out) {
    __shared__ float lds[64][CC + 2];
    __shared__ float psum[4][64];
    __shared__ float inv[64];
    int bid = blockIdx.x;            // n*1024 + h*4 + wq
    int wq = bid & 3;
    int h = (bid >> 2) & 255;
    int n = bid >> 10;
    int tid = threadIdx.x;
    int p = tid & 63;
    int cg = tid >> 6;
    size_t base = ((size_t)(n * CC) * HH + h) * WW + wq * 64 + p;
    float ss = 0.f;
    #pragma unroll
    for (int i = 0; i < 32; ++i) {
        int c = cg * 32 + i;
        float v = feat[base + (size_t)c * (HH * WW)];
        lds[p][c] = v;
        ss += v * v;
    }
    psum[cg][p] = ss;
    __syncthreads();
    if (tid < 64) {
        float s = psum[0][tid] + psum[1][tid] + psum[2][tid] + psum[3][tid];
        inv[tid] = FSCALE / fmaxf(sqrtf(s), 1e-12f);
    }
    __syncthreads();
    __hip_bfloat16* dst = out + (((size_t)n * HH + h) * WW + wq * 64) * CC;
    #pragma unroll
    for (int k = 0; k < 4; ++k) {
        int j = (k * 256 + tid) * 8;
        int pp = j >> 7;
        int c0 = j & 127;
        int g = c0 >> 3;
        int gs = g ^ (pp & 7);           // (wq*64+pp)&7 == pp&7
        float iv = inv[pp];
        __hip_bfloat16 tmp[8];
        #pragma unroll
        for (int i = 0; i < 8; ++i)
            tmp[i] = __float2bfloat16(lds[pp][c0 + i] * iv);
        *(uint4*)(dst + pp * 128 + gs * 8) = *(uint4*)tmp;
    }
}

// ---------------- Kernel B: LDS-staged banded-Gram MFMA loss, 4 rows/wave ----------------
// Block = 4 waves (256 thr), owns 4 rows x 64 cols; wave = 4 own rows x 16 cols.
// Two B-tiles (-8,+8) per staged row shared by ALL 4 A-row fragments.
// R9 schedule: TRIPLE buffer (3x20KB), depth-2 prefetch, ONE barrier/row:
//   per iter: vmcnt(5) [S(r) done, S(r+1) in flight] -> barrier -> STAGE(r+2)
//   -> ds_read+compute(r). Rotation makes STAGE(r+2) hit the buffer consumed
//   at r-1, which all waves finished before passing barrier(r).
// Select-before-exp (msel); masks/weights deferred to epilogue; features
// pre-scaled so exp(logit)=2^d.
// C layout (m89): col=lane&15 (neighbor), row=(lane>>4)*4+reg (own).
__global__ __launch_bounds__(256, 2) void loss_mfma(const char* __restrict__ fn,
                                                    float* __restrict__ out) {
    extern __shared__ char smem[];
    __shared__ float wsum[4];
    int bid = blockIdx.x;
    int swz = (bid & 7) * 128 + (bid >> 3);   // 1024 blocks, bijective XCD swizzle
    int n  = swz >> 8;
    int rg = (swz >> 2) & 63;
    int q  = swz & 3;
    int row0 = rg * 4;
    int c0 = q * 64;
    int tid = threadIdx.x;
    int wave = tid >> 6, lane = tid & 63;
    int nloc = lane & 15, kq = lane >> 4;
    int wbase = c0 + wave * 16;
    int sc0 = c0 - 8;

    const char* img = fn + (size_t)n * ((size_t)HH * ROWB);

    // A fragments: own rows row0..row0+3 at col wbase+nloc (swizzled layout)
    short8v a0[4], a1[4], a2[4], a3[4];
    {
        int px = wbase + nloc;
        const char* pb = img + (size_t)row0 * ROWB + px * 256;
        #pragma unroll
        for (int kb = 0; kb < 4; ++kb) a0[kb] = *(const short8v*)(pb + (((kb * 4 + kq) ^ (px & 7)) << 4));
        pb += ROWB;
        #pragma unroll
        for (int kb = 0; kb < 4; ++kb) a1[kb] = *(const short8v*)(pb + (((kb * 4 + kq) ^ (px & 7)) << 4));
        pb += ROWB;
        #pragma unroll
        for (int kb = 0; kb < 4; ++kb) a2[kb] = *(const short8v*)(pb + (((kb * 4 + kq) ^ (px & 7)) << 4));
        pb += ROWB;
        #pragma unroll
        for (int kb = 0; kb < 4; ++kb) a3[kb] = *(const short8v*)(pb + (((kb * 4 + kq) ^ (px & 7)) << 4));
    }

    // B-fragment LDS offsets (tiles at wbase-8, wbase+8), buffer-local, swizzle-matched
    int boff[2][4];
    #pragma unroll
    for (int j = 0; j < 2; ++j) {
        int colr = wbase - 8 + 16 * j + nloc;     // in [c0-8, c0+71]
        int lcol = colr - sc0;                    // 0..79
        int cc = min(max(colr, 0), WW - 1);
        #pragma unroll
        for (int kb = 0; kb < 4; ++kb)
            boff[j][kb] = lcol * 256 + (((kb * 4 + kq) ^ (cc & 7)) << 4);
    }

    // selection (tile1 valid?) + any-valid bits per rr; dy/row-invariant
    unsigned msel = 0, mb = 0;
    #pragma unroll
    for (int rr = 0; rr < 4; ++rr) {
        int rm = kq * 4 + rr;
        int dx0 = -8 + nloc - rm, dx1 = 8 + nloc - rm;
        int nc0 = wbase - 8 + nloc, nc1 = wbase + 8 + nloc;
        bool v0 = dx0 >= -NSS && dx0 <= NSS && nc0 >= 0 && nc0 < WW;
        bool v1 = dx1 >= -NSS && dx1 <= NSS && nc1 >= 0 && nc1 < WW;
        if (v1) msel |= 1u << rr;
        if (v0 || v1) mb |= 1u << rr;
    }

    // staging addresses: 1280 16B units, exactly 5 per thread
    int ss0, ss1, ss2, ss3, ss4;
    {
        int c_, cc_;
        c_ = tid;          cc_ = min(max(sc0 + (c_ >> 4), 0), WW - 1); ss0 = cc_ * 256 + ((c_ & 15) << 4);
        c_ = 256 + tid;    cc_ = min(max(sc0 + (c_ >> 4), 0), WW - 1); ss1 = cc_ * 256 + ((c_ & 15) << 4);
        c_ = 512 + tid;    cc_ = min(max(sc0 + (c_ >> 4), 0), WW - 1); ss2 = cc_ * 256 + ((c_ & 15) << 4);
        c_ = 768 + tid;    cc_ = min(max(sc0 + (c_ >> 4), 0), WW - 1); ss3 = cc_ * 256 + ((c_ & 15) << 4);
        c_ = 1024 + tid;   cc_ = min(max(sc0 + (c_ >> 4), 0), WW - 1); ss4 = cc_ * 256 + ((c_ & 15) << 4);
    }
#define STAGE(rr_, buf_) { \
    const char* srow_ = img + (size_t)(rr_) * ROWB; \
    gload_lds16(srow_ + ss0, (buf_) + (tid << 4)); \
    gload_lds16(srow_ + ss1, (buf_) + ((256 + tid) << 4)); \
    gload_lds16(srow_ + ss2, (buf_) + ((512 + tid) << 4)); \
    gload_lds16(srow_ + ss3, (buf_) + ((768 + tid) << 4)); \
    gload_lds16(srow_ + ss4, (buf_) + ((1024 + tid) << 4)); \
}

    float ea0[4], ea1[4], ea2[4], ea3[4];
    float ds0[4], ds1[4], ds2[4], ds3[4];
    #pragma unroll
    for (int rr = 0; rr < 4; ++rr) {
        ea0[rr] = EPSI; ea1[rr] = EPSI; ea2[rr] = EPSI; ea3[rr] = EPSI;
        ds0[rr] = 0.f;  ds1[rr] = 0.f;  ds2[rr] = 0.f;  ds3[rr] = 0.f;
    }

#define COMPUTE_T(T_, A_, EA_, DS_) \
    if (r >= row0 + (T_) - NSS && r <= row0 + (T_) + NSS) { \
        f32x4 c0 = {0.f, 0.f, 0.f, 0.f}, c1 = {0.f, 0.f, 0.f, 0.f}; \
        __builtin_amdgcn_s_setprio(1); \
        _Pragma("unroll") for (int kb = 0; kb < 4; ++kb) \
            c0 = __builtin_amdgcn_mfma_f32_16x16x32_bf16(A_[kb], b0[kb], c0, 0, 0, 0); \
        _Pragma("unroll") for (int kb = 0; kb < 4; ++kb) \
            c1 = __builtin_amdgcn_mfma_f32_16x16x32_bf16(A_[kb], b1[kb], c1, 0, 0, 0); \
        __builtin_amdgcn_s_setprio(0); \
        _Pragma("unroll") for (int rr = 0; rr < 4; ++rr) { \
            float d_ = ((msel >> rr) & 1) ? c1[rr] : c0[rr]; \
            EA_[rr] += exp2f(d_); DS_[rr] += d_; \
        } \
    }

    int rs = max(row0 - NSS, 0);
    int re = min(row0 + 3 + NSS, HH - 1);

    char* b_cur = smem;
    char* b_nxt = smem + SBYTES;
    char* b_fut = smem + 2 * SBYTES;

    STAGE(rs, b_cur);
    STAGE(rs + 1, b_nxt);        // window length >= 9, so rs+1 <= re always

    for (int r = rs; r <= re; ++r) {
        if (r < re) {
            // S(r) done (FIFO-oldest 5 retire); S(r+1)'s 5 may stay in flight
            asm volatile("s_waitcnt vmcnt(5)" ::: "memory");
        } else {
            asm volatile("s_waitcnt vmcnt(0)" ::: "memory");
        }
        __builtin_amdgcn_s_barrier();
        asm volatile("" ::: "memory");

        if (r + 2 <= re) STAGE(r + 2, b_fut);   // overwrites buffer consumed at r-1

        short8v b0[4], b1[4];
        #pragma unroll
        for (int kb = 0; kb < 4; ++kb) b0[kb] = *(const short8v*)(b_cur + boff[0][kb]);
        #pragma unroll
        for (int kb = 0; kb < 4; ++kb) b1[kb] = *(const short8v*)(b_cur + boff[1][kb]);

        COMPUTE_T(0, a0, ea0, ds0)
        COMPUTE_T(1, a1, ea1, ds1)
        COMPUTE_T(2, a2, ea2, ds2)
        COMPUTE_T(3, a3, ea3, ds3)

        char* t_ = b_cur; b_cur = b_nxt; b_nxt = b_fut; b_fut = t_;
    }

    // Epilogue: deferred masks, weights, reduce
    float acc = 0.f;
#define EPI_T(T_, EA_, DS_) { \
    int row = row0 + (T_); \
    float nvd = (float)(min(NSS, row) + min(NSS, HH - 1 - row) + 1); \
    _Pragma("unroll") for (int rr = 0; rr < 4; ++rr) { \
        int wm = wbase + kq * 4 + rr; \
        int nwd = min(NSS, wm) + min(NSS, WW - 1 - wm) + 1; \
        float iw = 1.0f / (nvd * (float)nwd); \
        float m_ = (mb & (1u << rr)) ? 1.0f : 0.0f; \
        acc += m_ * iw * (nvd * __logf(EA_[rr]) - LN2F * DS_[rr]); \
    } \
}
    EPI_T(0, ea0, ds0)
    EPI_T(1, ea1, ds1)
    EPI_T(2, ea2, ds2)
    EPI_T(3, ea3, ds3)

    float tot = acc * (1.0f / (4.0f * 65536.0f));
    #pragma unroll
    for (int off = 32; off >= 1; off >>= 1)
        tot += __shfl_down(tot, off);
    if (lane == 0) wsum[wave] = tot;
    __syncthreads();
    if (tid == 0) atomicAdd(out, wsum[0] + wsum[1] + wsum[2] + wsum[3]);
}

extern "C" void kernel_launch(void* const* d_in, const int* in_sizes, int n_in,
                              void* d_out, int out_size, void* d_ws, size_t ws_size,
                              hipStream_t stream) {
    const float* feat = (const float*)d_in[0];
    float* out = (float*)d_out;
    __hip_bfloat16* fnorm = (__hip_bfloat16*)d_ws;  // 64MB

    hipFuncSetAttribute(reinterpret_cast<const void*>(&loss_mfma),
                        hipFuncAttributeMaxDynamicSharedMemorySize, 3 * SBYTES);

    hipMemsetAsync(d_out, 0, sizeof(float), stream);
    norm_pack<<<NN * HH * (WW / 64), 256, 0, stream>>>(feat, fnorm);
    loss_mfma<<<NN * 64 * 4, 256, 3 * SBYTES, stream>>>((const char*)fnorm, out);
}

// Round 10
// 80.066 us; speedup vs baseline: 1.6624x; 1.0018x over previous
//
#include <hip/hip_runtime.h>
#include <hip/hip_bf16.h>

#define HH 256
#define WW 256
#define CC 128
#define NN 4
#define NSS 5
#define LN2F 0.6931471805599453f
#define FSCALE 3.79828245f      // sqrt(10*log2(e)); dot scales by 14.4269504089
#define EPSI 1e-6f
#define ROWB (WW * CC * 2)      // 65536 B per image row (256 px * 256 B)
#define SC 80                   // staged cols per row window (c0-8 .. c0+71)
#define SBYTES (SC * 256)       // 20480 B per staged row

typedef __attribute__((ext_vector_type(4))) float f32x4;
typedef __attribute__((ext_vector_type(8))) short short8v;

__device__ __forceinline__ void gload_lds16(const void* g, void* l) {
    __builtin_amdgcn_global_load_lds(
        (const __attribute__((address_space(1))) unsigned int*)g,
        (__attribute__((address_space(3))) unsigned int*)l, 16, 0, 0);
}

// ---------------- Kernel A: L2-normalize over C (x FSCALE), NCHW(f32) -> NHWC(bf16) -------
// granule-swizzled: 16B granule g of pixel w stored at slot g^(w&7)
__global__ __launch_bounds__(256) void norm_pack(const float* __restrict__ feat,
                                                 __hip_bfloat16* __restrict__ out) {
    __shared__ float lds[64][CC + 2];
    __shared__ float psum[4][64];
    __shared__ float inv[64];
    int bid = blockIdx.x;            // n*1024 + h*4 + wq
    int wq = bid & 3;
    int h = (bid >> 2) & 255;
    int n = bid >> 10;
    int tid = threadIdx.x;
    int p = tid & 63;
    int cg = tid >> 6;
    size_t base = ((size_t)(n * CC) * HH + h) * WW + wq * 64 + p;
    float ss = 0.f;
    #pragma unroll
    for (int i = 0; i < 32; ++i) {
        int c = cg * 32 + i;
        float v = feat[base + (size_t)c * (HH * WW)];
        lds[p][c] = v;
        ss += v * v;
    }
    psum[cg][p] = ss;
    __syncthreads();
    if (tid < 64) {
        float s = psum[0][tid] + psum[1][tid] + psum[2][tid] + psum[3][tid];
        inv[tid] = FSCALE / fmaxf(sqrtf(s), 1e-12f);
    }
    __syncthreads();
    __hip_bfloat16* dst = out + (((size_t)n * HH + h) * WW + wq * 64) * CC;
    #pragma unroll
    for (int k = 0; k < 4; ++k) {
        int j = (k * 256 + tid) * 8;
        int pp = j >> 7;
        int c0 = j & 127;
        int g = c0 >> 3;
        int gs = g ^ (pp & 7);           // (wq*64+pp)&7 == pp&7
        float iv = inv[pp];
        __hip_bfloat16 tmp[8];
        #pragma unroll
        for (int i = 0; i < 8; ++i)
            tmp[i] = __float2bfloat16(lds[pp][c0 + i] * iv);
        *(uint4*)(dst + pp * 128 + gs * 8) = *(uint4*)tmp;
    }
}

// ---------------- Kernel B: LDS-staged banded-Gram MFMA loss, 4 rows/wave ----------------
// Block = 4 waves (256 thr), owns 4 rows x 64 cols; wave = 4 own rows x 16 cols.
// Two B-tiles (-8,+8) per staged row shared by ALL 4 A-row fragments.
// R10: R8's two-barrier double-buffer schedule (race-free: per-wave vmcnt(5)
// before barrier gives cross-wave visibility of S(r)), at __launch_bounds__(256,3)
// -> 12 waves/CU (VGPR cap 170 under BOTH launch-bounds semantics), LDS 40KB
// -> 3 blocks/CU: three independent barrier-groups hide each other's stalls.
// Select-before-exp (msel); masks/weights deferred to epilogue; features
// pre-scaled so exp(logit)=2^d.
// C layout (m89): col=lane&15 (neighbor), row=(lane>>4)*4+reg (own).
__global__ __launch_bounds__(256, 3) void loss_mfma(const char* __restrict__ fn,
                                                    float* __restrict__ out) {
    extern __shared__ char smem[];
    __shared__ float wsum[4];
    int bid = blockIdx.x;
    int swz = (bid & 7) * 128 + (bid >> 3);   // 1024 blocks, bijective XCD swizzle
    int n  = swz >> 8;
    int rg = (swz >> 2) & 63;
    int q  = swz & 3;
    int row0 = rg * 4;
    int c0 = q * 64;
    int tid = threadIdx.x;
    int wave = tid >> 6, lane = tid & 63;
    int nloc = lane & 15, kq = lane >> 4;
    int wbase = c0 + wave * 16;
    int sc0 = c0 - 8;

    const char* img = fn + (size_t)n * ((size_t)HH * ROWB);

    // A fragments: own rows row0..row0+3 at col wbase+nloc (swizzled layout)
    short8v a0[4], a1[4], a2[4], a3[4];
    {
        int px = wbase + nloc;
        const char* pb = img + (size_t)row0 * ROWB + px * 256;
        #pragma unroll
        for (int kb = 0; kb < 4; ++kb) a0[kb] = *(const short8v*)(pb + (((kb * 4 + kq) ^ (px & 7)) << 4));
        pb += ROWB;
        #pragma unroll
        for (int kb = 0; kb < 4; ++kb) a1[kb] = *(const short8v*)(pb + (((kb * 4 + kq) ^ (px & 7)) << 4));
        pb += ROWB;
        #pragma unroll
        for (int kb = 0; kb < 4; ++kb) a2[kb] = *(const short8v*)(pb + (((kb * 4 + kq) ^ (px & 7)) << 4));
        pb += ROWB;
        #pragma unroll
        for (int kb = 0; kb < 4; ++kb) a3[kb] = *(const short8v*)(pb + (((kb * 4 + kq) ^ (px & 7)) << 4));
    }

    // B-fragment LDS offsets (tiles at wbase-8, wbase+8), buffer-local, swizzle-matched
    int boff[2][4];
    #pragma unroll
    for (int j = 0; j < 2; ++j) {
        int colr = wbase - 8 + 16 * j + nloc;     // in [c0-8, c0+71]
        int lcol = colr - sc0;                    // 0..79
        int cc = min(max(colr, 0), WW - 1);
        #pragma unroll
        for (int kb = 0; kb < 4; ++kb)
            boff[j][kb] = lcol * 256 + (((kb * 4 + kq) ^ (cc & 7)) << 4);
    }

    // selection (tile1 valid?) + any-valid bits per rr; dy/row-invariant
    unsigned msel = 0, mb = 0;
    #pragma unroll
    for (int rr = 0; rr < 4; ++rr) {
        int rm = kq * 4 + rr;
        int dx0 = -8 + nloc - rm, dx1 = 8 + nloc - rm;
        int nc0 = wbase - 8 + nloc, nc1 = wbase + 8 + nloc;
        bool v0 = dx0 >= -NSS && dx0 <= NSS && nc0 >= 0 && nc0 < WW;
        bool v1 = dx1 >= -NSS && dx1 <= NSS && nc1 >= 0 && nc1 < WW;
        if (v1) msel |= 1u << rr;
        if (v0 || v1) mb |= 1u << rr;
    }

    // staging addresses: 1280 16B units, exactly 5 per thread
    int ss0, ss1, ss2, ss3, ss4;
    {
        int c_, cc_;
        c_ = tid;          cc_ = min(max(sc0 + (c_ >> 4), 0), WW - 1); ss0 = cc_ * 256 + ((c_ & 15) << 4);
        c_ = 256 + tid;    cc_ = min(max(sc0 + (c_ >> 4), 0), WW - 1); ss1 = cc_ * 256 + ((c_ & 15) << 4);
        c_ = 512 + tid;    cc_ = min(max(sc0 + (c_ >> 4), 0), WW - 1); ss2 = cc_ * 256 + ((c_ & 15) << 4);
        c_ = 768 + tid;    cc_ = min(max(sc0 + (c_ >> 4), 0), WW - 1); ss3 = cc_ * 256 + ((c_ & 15) << 4);
        c_ = 1024 + tid;   cc_ = min(max(sc0 + (c_ >> 4), 0), WW - 1); ss4 = cc_ * 256 + ((c_ & 15) << 4);
    }
#define STAGE(rr_, buf_) { \
    const char* srow_ = img + (size_t)(rr_) * ROWB; \
    gload_lds16(srow_ + ss0, (buf_) + (tid << 4)); \
    gload_lds16(srow_ + ss1, (buf_) + ((256 + tid) << 4)); \
    gload_lds16(srow_ + ss2, (buf_) + ((512 + tid) << 4)); \
    gload_lds16(srow_ + ss3, (buf_) + ((768 + tid) << 4)); \
    gload_lds16(srow_ + ss4, (buf_) + ((1024 + tid) << 4)); \
}

    float ea0[4], ea1[4], ea2[4], ea3[4];
    float ds0[4], ds1[4], ds2[4], ds3[4];
    #pragma unroll
    for (int rr = 0; rr < 4; ++rr) {
        ea0[rr] = EPSI; ea1[rr] = EPSI; ea2[rr] = EPSI; ea3[rr] = EPSI;
        ds0[rr] = 0.f;  ds1[rr] = 0.f;  ds2[rr] = 0.f;  ds3[rr] = 0.f;
    }

#define COMPUTE_T(T_, A_, EA_, DS_) \
    if (r >= row0 + (T_) - NSS && r <= row0 + (T_) + NSS) { \
        f32x4 c0 = {0.f, 0.f, 0.f, 0.f}, c1 = {0.f, 0.f, 0.f, 0.f}; \
        __builtin_amdgcn_s_setprio(1); \
        _Pragma("unroll") for (int kb = 0; kb < 4; ++kb) \
            c0 = __builtin_amdgcn_mfma_f32_16x16x32_bf16(A_[kb], b0[kb], c0, 0, 0, 0); \
        _Pragma("unroll") for (int kb = 0; kb < 4; ++kb) \
            c1 = __builtin_amdgcn_mfma_f32_16x16x32_bf16(A_[kb], b1[kb], c1, 0, 0, 0); \
        __builtin_amdgcn_s_setprio(0); \
        _Pragma("unroll") for (int rr = 0; rr < 4; ++rr) { \
            float d_ = ((msel >> rr) & 1) ? c1[rr] : c0[rr]; \
            EA_[rr] += exp2f(d_); DS_[rr] += d_; \
        } \
    }

    int rs = max(row0 - NSS, 0);
    int re = min(row0 + 3 + NSS, HH - 1);

    STAGE(rs, smem);

    for (int r = rs; r <= re; ++r) {
        char* cbuf = smem + ((r - rs) & 1) * SBYTES;
        if (r < re) {
            char* nbuf = smem + ((((r - rs) & 1) ^ 1) * SBYTES);
            STAGE(r + 1, nbuf);
            asm volatile("s_waitcnt vmcnt(5)" ::: "memory");  // S(r) done; S(r+1) in flight
        } else {
            asm volatile("s_waitcnt vmcnt(0)" ::: "memory");
        }
        __builtin_amdgcn_s_barrier();
        asm volatile("" ::: "memory");

        short8v b0[4], b1[4];
        #pragma unroll
        for (int kb = 0; kb < 4; ++kb) b0[kb] = *(const short8v*)(cbuf + boff[0][kb]);
        #pragma unroll
        for (int kb = 0; kb < 4; ++kb) b1[kb] = *(const short8v*)(cbuf + boff[1][kb]);

        COMPUTE_T(0, a0, ea0, ds0)
        COMPUTE_T(1, a1, ea1, ds1)
        COMPUTE_T(2, a2, ea2, ds2)
        COMPUTE_T(3, a3, ea3, ds3)

        __builtin_amdgcn_s_barrier();
    }

    // Epilogue: deferred masks, weights, reduce
    float acc = 0.f;
#define EPI_T(T_, EA_, DS_) { \
    int row = row0 + (T_); \
    float nvd = (float)(min(NSS, row) + min(NSS, HH - 1 - row) + 1); \
    _Pragma("unroll") for (int rr = 0; rr < 4; ++rr) { \
        int wm = wbase + kq * 4 + rr; \
        int nwd = min(NSS, wm) + min(NSS, WW - 1 - wm) + 1; \
        float iw = 1.0f / (nvd * (float)nwd); \
        float m_ = (mb & (1u << rr)) ? 1.0f : 0.0f; \
        acc += m_ * iw * (nvd * __logf(EA_[rr]) - LN2F * DS_[rr]); \
    } \
}
    EPI_T(0, ea0, ds0)
    EPI_T(1, ea1, ds1)
    EPI_T(2, ea2, ds2)
    EPI_T(3, ea3, ds3)

    float tot = acc * (1.0f / (4.0f * 65536.0f));
    #pragma unroll
    for (int off = 32; off >= 1; off >>= 1)
        tot += __shfl_down(tot, off);
    if (lane == 0) wsum[wave] = tot;
    __syncthreads();
    if (tid == 0) atomicAdd(out, wsum[0] + wsum[1] + wsum[2] + wsum[3]);
}

extern "C" void kernel_launch(void* const* d_in, const int* in_sizes, int n_in,
                              void* d_out, int out_size, void* d_ws, size_t ws_size,
                              hipStream_t stream) {
    const float* feat = (const float*)d_in[0];
    float* out = (float*)d_out;
    __hip_bfloat16* fnorm = (__hip_bfloat16*)d_ws;  // 64MB

    hipFuncSetAttribute(reinterpret_cast<const void*>(&loss_mfma),
                        hipFuncAttributeMaxDynamicSharedMemorySize, 2 * SBYTES);

    hipMemsetAsync(d_out, 0, sizeof(float), stream);
    norm_pack<<<NN * HH * (WW / 64), 256, 0, stream>>>(feat, fnorm);
    loss_mfma<<<NN * 64 * 4, 256, 2 * SBYTES, stream>>>((const char*)fnorm, out);
}

// Round 11
// 75.922 us; speedup vs baseline: 1.7532x; 1.0546x over previous
//
#include <hip/hip_runtime.h>
#include <hip/hip_bf16.h>

#define HH 256
#define WW 256
#define CC 128
#define NN 4
#define NSS 5
#define LN2F 0.6931471805599453f
#define FSCALE 3.79828245f      // sqrt(10*log2(e)); dot scales by 14.4269504089
#define EPSI 1e-6f
#define ROWB (WW * CC * 2)      // 65536 B per image row (256 px * 256 B)
#define SC 80                   // staged cols per row window (c0-8 .. c0+71)
#define SBYTES (SC * 256)       // 20480 B per staged row

typedef __attribute__((ext_vector_type(4))) float f32x4;
typedef __attribute__((ext_vector_type(8))) short short8v;

__device__ __forceinline__ void gload_lds16(const void* g, void* l) {
    __builtin_amdgcn_global_load_lds(
        (const __attribute__((address_space(1))) unsigned int*)g,
        (__attribute__((address_space(3))) unsigned int*)l, 16, 0, 0);
}

__device__ __forceinline__ float fast_exp2(float x) {
    float r;
    asm("v_exp_f32 %0, %1" : "=v"(r) : "v"(x));
    return r;
}
__device__ __forceinline__ float fast_log2(float x) {
    float r;
    asm("v_log_f32 %0, %1" : "=v"(r) : "v"(x));
    return r;
}

// ---------------- Kernel A: L2-normalize over C (x FSCALE), NCHW(f32) -> NHWC(bf16) -------
// granule-swizzled: 16B granule g of pixel w stored at slot g^(w&7)
__global__ __launch_bounds__(256) void norm_pack(const float* __restrict__ feat,
                                                 __hip_bfloat16* __restrict__ out) {
    __shared__ float lds[64][CC + 2];
    __shared__ float psum[4][64];
    __shared__ float inv[64];
    int bid = blockIdx.x;            // n*1024 + h*4 + wq
    int wq = bid & 3;
    int h = (bid >> 2) & 255;
    int n = bid >> 10;
    int tid = threadIdx.x;
    int p = tid & 63;
    int cg = tid >> 6;
    size_t base = ((size_t)(n * CC) * HH + h) * WW + wq * 64 + p;
    float ss = 0.f;
    #pragma unroll
    for (int i = 0; i < 32; ++i) {
        int c = cg * 32 + i;
        float v = feat[base + (size_t)c * (HH * WW)];
        lds[p][c] = v;
        ss += v * v;
    }
    psum[cg][p] = ss;
    __syncthreads();
    if (tid < 64) {
        float s = psum[0][tid] + psum[1][tid] + psum[2][tid] + psum[3][tid];
        inv[tid] = FSCALE / fmaxf(sqrtf(s), 1e-12f);
    }
    __syncthreads();
    __hip_bfloat16* dst = out + (((size_t)n * HH + h) * WW + wq * 64) * CC;
    #pragma unroll
    for (int k = 0; k < 4; ++k) {
        int j = (k * 256 + tid) * 8;
        int pp = j >> 7;
        int c0 = j & 127;
        int g = c0 >> 3;
        int gs = g ^ (pp & 7);           // (wq*64+pp)&7 == pp&7
        float iv = inv[pp];
        __hip_bfloat16 tmp[8];
        #pragma unroll
        for (int i = 0; i < 8; ++i)
            tmp[i] = __float2bfloat16(lds[pp][c0 + i] * iv);
        *(uint4*)(dst + pp * 128 + gs * 8) = *(uint4*)tmp;
    }
}

// ---------------- Kernel B: LDS-staged banded-Gram MFMA loss, 4 rows/wave ----------------
// R11 = R10 structure exactly, with libm exp2f/__logf replaced by bare
// v_exp_f32 / v_log_f32 (inputs |d|<=14.43: normal range, no ocml guards needed).
// Block = 4 waves, owns 4 rows x 64 cols; wave = 4 own rows x 16 cols.
// Two-barrier double-buffer, depth-1 prefetch, counted vmcnt(5).
// Select-before-exp (msel); masks/weights deferred to epilogue; features
// pre-scaled so exp(logit)=2^d.
// C layout (m89): col=lane&15 (neighbor), row=(lane>>4)*4+reg (own).
__global__ __launch_bounds__(256, 3) void loss_mfma(const char* __restrict__ fn,
                                                    float* __restrict__ out) {
    extern __shared__ char smem[];
    __shared__ float wsum[4];
    int bid = blockIdx.x;
    int swz = (bid & 7) * 128 + (bid >> 3);   // 1024 blocks, bijective XCD swizzle
    int n  = swz >> 8;
    int rg = (swz >> 2) & 63;
    int q  = swz & 3;
    int row0 = rg * 4;
    int c0 = q * 64;
    int tid = threadIdx.x;
    int wave = tid >> 6, lane = tid & 63;
    int nloc = lane & 15, kq = lane >> 4;
    int wbase = c0 + wave * 16;
    int sc0 = c0 - 8;

    const char* img = fn + (size_t)n * ((size_t)HH * ROWB);

    // A fragments: own rows row0..row0+3 at col wbase+nloc (swizzled layout)
    short8v a0[4], a1[4], a2[4], a3[4];
    {
        int px = wbase + nloc;
        const char* pb = img + (size_t)row0 * ROWB + px * 256;
        #pragma unroll
        for (int kb = 0; kb < 4; ++kb) a0[kb] = *(const short8v*)(pb + (((kb * 4 + kq) ^ (px & 7)) << 4));
        pb += ROWB;
        #pragma unroll
        for (int kb = 0; kb < 4; ++kb) a1[kb] = *(const short8v*)(pb + (((kb * 4 + kq) ^ (px & 7)) << 4));
        pb += ROWB;
        #pragma unroll
        for (int kb = 0; kb < 4; ++kb) a2[kb] = *(const short8v*)(pb + (((kb * 4 + kq) ^ (px & 7)) << 4));
        pb += ROWB;
        #pragma unroll
        for (int kb = 0; kb < 4; ++kb) a3[kb] = *(const short8v*)(pb + (((kb * 4 + kq) ^ (px & 7)) << 4));
    }

    // B-fragment LDS offsets (tiles at wbase-8, wbase+8), buffer-local, swizzle-matched
    int boff[2][4];
    #pragma unroll
    for (int j = 0; j < 2; ++j) {
        int colr = wbase - 8 + 16 * j + nloc;     // in [c0-8, c0+71]
        int lcol = colr - sc0;                    // 0..79
        int cc = min(max(colr, 0), WW - 1);
        #pragma unroll
        for (int kb = 0; kb < 4; ++kb)
            boff[j][kb] = lcol * 256 + (((kb * 4 + kq) ^ (cc & 7)) << 4);
    }

    // selection (tile1 valid?) + any-valid bits per rr; dy/row-invariant
    unsigned msel = 0, mb = 0;
    #pragma unroll
    for (int rr = 0; rr < 4; ++rr) {
        int rm = kq * 4 + rr;
        int dx0 = -8 + nloc - rm, dx1 = 8 + nloc - rm;
        int nc0 = wbase - 8 + nloc, nc1 = wbase + 8 + nloc;
        bool v0 = dx0 >= -NSS && dx0 <= NSS && nc0 >= 0 && nc0 < WW;
        bool v1 = dx1 >= -NSS && dx1 <= NSS && nc1 >= 0 && nc1 < WW;
        if (v1) msel |= 1u << rr;
        if (v0 || v1) mb |= 1u << rr;
    }

    // staging addresses: 1280 16B units, exactly 5 per thread
    int ss0, ss1, ss2, ss3, ss4;
    {
        int c_, cc_;
        c_ = tid;          cc_ = min(max(sc0 + (c_ >> 4), 0), WW - 1); ss0 = cc_ * 256 + ((c_ & 15) << 4);
        c_ = 256 + tid;    cc_ = min(max(sc0 + (c_ >> 4), 0), WW - 1); ss1 = cc_ * 256 + ((c_ & 15) << 4);
        c_ = 512 + tid;    cc_ = min(max(sc0 + (c_ >> 4), 0), WW - 1); ss2 = cc_ * 256 + ((c_ & 15) << 4);
        c_ = 768 + tid;    cc_ = min(max(sc0 + (c_ >> 4), 0), WW - 1); ss3 = cc_ * 256 + ((c_ & 15) << 4);
        c_ = 1024 + tid;   cc_ = min(max(sc0 + (c_ >> 4), 0), WW - 1); ss4 = cc_ * 256 + ((c_ & 15) << 4);
    }
#define STAGE(rr_, buf_) { \
    const char* srow_ = img + (size_t)(rr_) * ROWB; \
    gload_lds16(srow_ + ss0, (buf_) + (tid << 4)); \
    gload_lds16(srow_ + ss1, (buf_) + ((256 + tid) << 4)); \
    gload_lds16(srow_ + ss2, (buf_) + ((512 + tid) << 4)); \
    gload_lds16(srow_ + ss3, (buf_) + ((768 + tid) << 4)); \
    gload_lds16(srow_ + ss4, (buf_) + ((1024 + tid) << 4)); \
}

    float ea0[4], ea1[4], ea2[4], ea3[4];
    float ds0[4], ds1[4], ds2[4], ds3[4];
    #pragma unroll
    for (int rr = 0; rr < 4; ++rr) {
        ea0[rr] = EPSI; ea1[rr] = EPSI; ea2[rr] = EPSI; ea3[rr] = EPSI;
        ds0[rr] = 0.f;  ds1[rr] = 0.f;  ds2[rr] = 0.f;  ds3[rr] = 0.f;
    }

#define COMPUTE_T(T_, A_, EA_, DS_) \
    if (r >= row0 + (T_) - NSS && r <= row0 + (T_) + NSS) { \
        f32x4 c0 = {0.f, 0.f, 0.f, 0.f}, c1 = {0.f, 0.f, 0.f, 0.f}; \
        __builtin_amdgcn_s_setprio(1); \
        _Pragma("unroll") for (int kb = 0; kb < 4; ++kb) \
            c0 = __builtin_amdgcn_mfma_f32_16x16x32_bf16(A_[kb], b0[kb], c0, 0, 0, 0); \
        _Pragma("unroll") for (int kb = 0; kb < 4; ++kb) \
            c1 = __builtin_amdgcn_mfma_f32_16x16x32_bf16(A_[kb], b1[kb], c1, 0, 0, 0); \
        __builtin_amdgcn_s_setprio(0); \
        _Pragma("unroll") for (int rr = 0; rr < 4; ++rr) { \
            float d_ = ((msel >> rr) & 1) ? c1[rr] : c0[rr]; \
            EA_[rr] += fast_exp2(d_); DS_[rr] += d_; \
        } \
    }

    int rs = max(row0 - NSS, 0);
    int re = min(row0 + 3 + NSS, HH - 1);

    STAGE(rs, smem);

    for (int r = rs; r <= re; ++r) {
        char* cbuf = smem + ((r - rs) & 1) * SBYTES;
        if (r < re) {
            char* nbuf = smem + ((((r - rs) & 1) ^ 1) * SBYTES);
            STAGE(r + 1, nbuf);
            asm volatile("s_waitcnt vmcnt(5)" ::: "memory");  // S(r) done; S(r+1) in flight
        } else {
            asm volatile("s_waitcnt vmcnt(0)" ::: "memory");
        }
        __builtin_amdgcn_s_barrier();
        asm volatile("" ::: "memory");

        short8v b0[4], b1[4];
        #pragma unroll
        for (int kb = 0; kb < 4; ++kb) b0[kb] = *(const short8v*)(cbuf + boff[0][kb]);
        #pragma unroll
        for (int kb = 0; kb < 4; ++kb) b1[kb] = *(const short8v*)(cbuf + boff[1][kb]);

        COMPUTE_T(0, a0, ea0, ds0)
        COMPUTE_T(1, a1, ea1, ds1)
        COMPUTE_T(2, a2, ea2, ds2)
        COMPUTE_T(3, a3, ea3, ds3)

        __builtin_amdgcn_s_barrier();
    }

    // Epilogue: deferred masks, weights, reduce (log2 form: ln(x)=LN2*log2(x))
    float acc = 0.f;
#define EPI_T(T_, EA_, DS_) { \
    int row = row0 + (T_); \
    float nvd = (float)(min(NSS, row) + min(NSS, HH - 1 - row) + 1); \
    _Pragma("unroll") for (int rr = 0; rr < 4; ++rr) { \
        int wm = wbase + kq * 4 + rr; \
        int nwd = min(NSS, wm) + min(NSS, WW - 1 - wm) + 1; \
        float iw = LN2F / (nvd * (float)nwd); \
        float m_ = (mb & (1u << rr)) ? 1.0f : 0.0f; \
        acc += m_ * iw * (nvd * fast_log2(EA_[rr]) - DS_[rr]); \
    } \
}
    EPI_T(0, ea0, ds0)
    EPI_T(1, ea1, ds1)
    EPI_T(2, ea2, ds2)
    EPI_T(3, ea3, ds3)

    float tot = acc * (1.0f / (4.0f * 65536.0f));
    #pragma unroll
    for (int off = 32; off >= 1; off >>= 1)
        tot += __shfl_down(tot, off);
    if (lane == 0) wsum[wave] = tot;
    __syncthreads();
    if (tid == 0) atomicAdd(out, wsum[0] + wsum[1] + wsum[2] + wsum[3]);
}

extern "C" void kernel_launch(void* const* d_in, const int* in_sizes, int n_in,
                              void* d_out, int out_size, void* d_ws, size_t ws_size,
                              hipStream_t stream) {
    const float* feat = (const float*)d_in[0];
    float* out = (float*)d_out;
    __hip_bfloat16* fnorm = (__hip_bfloat16*)d_ws;  // 64MB

    hipFuncSetAttribute(reinterpret_cast<const void*>(&loss_mfma),
                        hipFuncAttributeMaxDynamicSharedMemorySize, 2 * SBYTES);

    hipMemsetAsync(d_out, 0, sizeof(float), stream);
    norm_pack<<<NN * HH * (WW / 64), 256, 0, stream>>>(feat, fnorm);
    loss_mfma<<<NN * 64 * 4, 256, 2 * SBYTES, stream>>>((const char*)fnorm, out);
}